// Round 1
// baseline (180.694 us; speedup 1.0000x reference)
//
#include <hip/hip_runtime.h>

// Bicubic x0.5 antialiased resize, (32,3,512,512) f32 -> (32,3,256,256) f32.
// Derived structure: separable 8-tap stride-2 convolution, weights constant
// across output positions, source index = mirror(2*o + i - 3).
// Weights are read from the provided table (w[i*256]) rather than hard-coded.

#define H_IN   512
#define W_IN   512
#define H_OUT  256
#define W_OUT  256
#define BC     96      // 32 batch * 3 channels
#define TAPS   8
#define OHC    16      // output rows per thread in pass 1
#define OWC    8       // output cols per thread in pass 2

__device__ __forceinline__ int mir(int r, int n) {
    // mirror boundary, valid for r in [-n, 2n-1]
    r = (r < 0) ? (-1 - r) : r;
    r = (r >= n) ? (2 * n - 1 - r) : r;
    return r;
}

// Pass 1: resize along H.  in (96,512,512) -> mid (96,256,512)
// Thread: one float4 column strip (4 consecutive w) x 16 consecutive output
// rows. Rolling window: each needed input row loaded exactly once.
__global__ __launch_bounds__(256) void pass1(const float* __restrict__ in,
                                             const float* __restrict__ wt,
                                             float* __restrict__ mid) {
    int g   = blockIdx.x * 256 + threadIdx.x;
    int w4  = g & 127;          // 128 float4 per row
    int ohc = (g >> 7) & 15;    // 16 chunks of OHC rows
    int bc  = g >> 11;          // 96

    int oh0 = ohc * OHC;

    float K[TAPS];
#pragma unroll
    for (int i = 0; i < TAPS; ++i) K[i] = wt[i * H_OUT];  // same for all oh

    const float4* src = (const float4*)(in + (size_t)bc * H_IN * W_IN) + w4;

    float4 acc[OHC];
#pragma unroll
    for (int k = 0; k < OHC; ++k) acc[k] = make_float4(0.f, 0.f, 0.f, 0.f);

    const int rbase = 2 * oh0 - 3;
#pragma unroll
    for (int rr = 0; rr < 2 * OHC + 6; ++rr) {
        int rm = mir(rbase + rr, H_IN);
        float4 x = src[(size_t)rm * (W_IN / 4)];
#pragma unroll
        for (int k = 0; k < OHC; ++k) {
            int i = rr - 2 * k;               // compile-time per (rr,k)
            if (0 <= i && i < TAPS) {
                float kw = K[i];
                acc[k].x += kw * x.x;
                acc[k].y += kw * x.y;
                acc[k].z += kw * x.z;
                acc[k].w += kw * x.w;
            }
        }
    }

    float4* dst = (float4*)(mid + (size_t)bc * H_OUT * W_IN) + w4;
#pragma unroll
    for (int k = 0; k < OHC; ++k)
        dst[(size_t)(oh0 + k) * (W_IN / 4)] = acc[k];
}

// Pass 2: resize along W.  mid (96,256,512) -> out (96,256,256)
// Thread: 8 consecutive output cols of one row; 22-float rolling window.
__global__ __launch_bounds__(256) void pass2(const float* __restrict__ mid,
                                             const float* __restrict__ wt,
                                             float* __restrict__ out) {
    int g   = blockIdx.x * 256 + threadIdx.x;
    int owc = g & 31;           // 32 chunks of OWC cols
    int oh  = (g >> 5) & 255;
    int bc  = g >> 13;          // 96

    int ow0 = owc * OWC;

    float K[TAPS];
#pragma unroll
    for (int i = 0; i < TAPS; ++i) K[i] = wt[i * W_OUT];

    const float* src = mid + ((size_t)bc * H_OUT + oh) * W_IN;

    float win[2 * OWC + 6];
    const int cbase = 2 * ow0 - 3;
#pragma unroll
    for (int t = 0; t < 2 * OWC + 6; ++t)
        win[t] = src[mir(cbase + t, W_IN)];

    float res[OWC];
#pragma unroll
    for (int k = 0; k < OWC; ++k) {
        float s = 0.f;
#pragma unroll
        for (int j = 0; j < TAPS; ++j)
            s += K[j] * win[2 * k + j];
        res[k] = s;
    }

    float* dstrow = out + ((size_t)bc * H_OUT + oh) * W_OUT + ow0;
    float4* dv = (float4*)dstrow;   // ow0 is a multiple of 8 -> 32B aligned
    dv[0] = make_float4(res[0], res[1], res[2], res[3]);
    dv[1] = make_float4(res[4], res[5], res[6], res[7]);
}

// Fallback if workspace is too small for the 50.3 MB intermediate:
// fully fused per-output-pixel kernel (slower, still correct).
__global__ __launch_bounds__(256) void fused(const float* __restrict__ in,
                                             const float* __restrict__ wt,
                                             float* __restrict__ out) {
    int g = blockIdx.x * 256 + threadIdx.x;
    if (g >= BC * H_OUT * W_OUT) return;
    int ow = g & 255;
    int oh = (g >> 8) & 255;
    int bc = g >> 16;

    float K[TAPS];
#pragma unroll
    for (int i = 0; i < TAPS; ++i) K[i] = wt[i * H_OUT];

    float s = 0.f;
#pragma unroll
    for (int i = 0; i < TAPS; ++i) {
        const float* row =
            in + ((size_t)bc * H_IN + mir(2 * oh + i - 3, H_IN)) * W_IN;
        float t = 0.f;
#pragma unroll
        for (int j = 0; j < TAPS; ++j)
            t += K[j] * row[mir(2 * ow + j - 3, W_IN)];
        s += K[i] * t;
    }
    out[g] = s;
}

extern "C" void kernel_launch(void* const* d_in, const int* in_sizes, int n_in,
                              void* d_out, int out_size, void* d_ws, size_t ws_size,
                              hipStream_t stream) {
    const float* in = (const float*)d_in[0];
    const float* w2 = (const float*)d_in[1];  // (taps,256,1,1,1) flat, H weights
    const float* w3 = (const float*)d_in[3];  // identical table, W weights
    float* out = (float*)d_out;

    const size_t mid_bytes = (size_t)BC * H_OUT * W_IN * sizeof(float);

    if (ws_size >= mid_bytes) {
        float* mid = (float*)d_ws;
        // pass1: 96 bc * 16 chunks * 128 float4 = 196608 threads
        pass1<<<(BC * 16 * 128) / 256, 256, 0, stream>>>(in, w2, mid);
        // pass2: 96 bc * 256 rows * 32 chunks = 786432 threads
        pass2<<<(BC * 256 * 32) / 256, 256, 0, stream>>>(mid, w3, out);
    } else {
        fused<<<(BC * H_OUT * W_OUT + 255) / 256, 256, 0, stream>>>(in, w2, out);
    }
}

// Round 2
// 158.508 us; speedup vs baseline: 1.1400x; 1.1400x over previous
//
#include <hip/hip_runtime.h>

// Bicubic x0.5 antialiased resize, (32,3,512,512) f32 -> (32,3,256,256) f32.
// Structure (derived from reference contributions math, verified in R1):
//   separable 8-tap stride-2 convolution, weights identical for every output
//   position (read from wt[i*256]), source index = mirror(2*o + i - 3).
// Single fused kernel: H-pass into LDS tile, W-pass from LDS. No workspace,
// no intermediate HBM round-trip.

#define H_IN   512
#define W_IN   512
#define H_OUT  256
#define W_OUT  256
#define BC     96          // 32 batch * 3 channels
#define TAPS   8
#define OH_T   8           // output rows per block
#define OW_T   128         // output cols per block
#define IN_ROWS (2 * OH_T + 6)    // 22 input rows per block
#define MID_COLS (2 * OW_T + 6)   // 262 mid columns per block

__device__ __forceinline__ int mir(int r, int n) {
    // mirror boundary, valid for r in [-n, 2n-1]
    r = (r < 0) ? (-1 - r) : r;
    r = (r >= n) ? (2 * n - 1 - r) : r;
    return r;
}

__global__ __launch_bounds__(256) void resize_fused(const float* __restrict__ in,
                                                    const float* __restrict__ wt,
                                                    float* __restrict__ out) {
    __shared__ float mid[OH_T][MID_COLS];   // 8.4 KB; phase-B stride-2 reads
                                            // are 2 lanes/bank -> conflict-free

    const int bid = blockIdx.x;
    const int owt = bid & 1;                // 2 col tiles
    const int oht = (bid >> 1) & 31;        // 32 row tiles
    const int bc  = bid >> 6;               // 96 images
    const int oh0 = oht * OH_T;
    const int ow0 = owt * OW_T;
    const int t   = threadIdx.x;

    float K[TAPS];
#pragma unroll
    for (int i = 0; i < TAPS; ++i) K[i] = wt[i * H_OUT];  // constant over oc

    const float* src = in + (size_t)bc * H_IN * W_IN;
    const int rbase = 2 * oh0 - 3;
    const int cbase = 2 * ow0 - 3;

    // ---- Phase A: H-pass. Thread t handles mid column(s) c = t (+256).
    // Coalesced: lanes read consecutive input columns per row. Rolling
    // register window: each input element read exactly once per block.
    for (int c = t; c < MID_COLS; c += 256) {
        const int gc = mir(cbase + c, W_IN);
        float acc[OH_T];
#pragma unroll
        for (int k = 0; k < OH_T; ++k) acc[k] = 0.f;

#pragma unroll
        for (int r = 0; r < IN_ROWS; ++r) {
            const float x = src[(size_t)mir(rbase + r, H_IN) * W_IN + gc];
#pragma unroll
            for (int k = 0; k < OH_T; ++k) {
                const int i = r - 2 * k;       // resolved at compile time
                if (0 <= i && i < TAPS) acc[k] += K[i] * x;
            }
        }
#pragma unroll
        for (int k = 0; k < OH_T; ++k) mid[k][c] = acc[k];
    }

    __syncthreads();

    // ---- Phase B: W-pass from LDS. Thread t: one output column, 4 rows.
    const int owl = t & (OW_T - 1);         // 0..127
    const int r0  = (t >> 7) * 4;           // 0 or 4
    float* dst = out + ((size_t)bc * H_OUT + oh0) * W_OUT + ow0 + owl;

#pragma unroll
    for (int rr = 0; rr < 4; ++rr) {
        const int row = r0 + rr;
        float s = 0.f;
#pragma unroll
        for (int j = 0; j < TAPS; ++j)
            s += K[j] * mid[row][2 * owl + j];   // local col: window starts at 2*owl
        dst[(size_t)row * W_OUT] = s;
    }
}

extern "C" void kernel_launch(void* const* d_in, const int* in_sizes, int n_in,
                              void* d_out, int out_size, void* d_ws, size_t ws_size,
                              hipStream_t stream) {
    const float* in = (const float*)d_in[0];
    const float* w2 = (const float*)d_in[1];  // (taps,256,1,1,1) flat
    float* out = (float*)d_out;
    (void)d_ws; (void)ws_size;

    // 96 bc * 32 row tiles * 2 col tiles = 6144 blocks (24 per CU)
    resize_fused<<<BC * 32 * 2, 256, 0, stream>>>(in, w2, out);
}